// Round 7
// baseline (253.582 us; speedup 1.0000x reference)
//
#include <hip/hip_runtime.h>
#include <hip/hip_fp16.h>

#define NNODES 100000
#define NB 391         // coarse buckets: node >> 8 (256 nodes each)
#define NXF 1563       // xform-role blocks in fused kernel
#define BSHIFT 8
#define BMASK 255
#define BCAP 4864      // per-bucket capacity (avg 4092, sigma ~64 -> +12 sigma)
#define WT_LD 136      // padded k-stride (halves) for transposed W1

typedef _Float16 half8 __attribute__((ext_vector_type(8)));
typedef float floatx4 __attribute__((ext_vector_type(4)));

// ---- K2: binA (+ global deg count) + prep block ----
// Blocks 0..390: coarse-bin edges (R11 shape) + deg atomics (enables binB2||xform).
// Block 391: w23 fold + W1 transpose/fp16 (no bcnt dependency).
__global__ __launch_bounds__(256) void binAP_kernel(
        const int* __restrict__ src, const int* __restrict__ dst,
        int* __restrict__ bcnt, unsigned* __restrict__ bdata, int E,
        int* __restrict__ deg_g,
        const float* __restrict__ W1, const float* __restrict__ W2,
        const float* __restrict__ b2, const float* __restrict__ W3,
        float* __restrict__ w23, __half* __restrict__ Wt) {
    if (blockIdx.x == NB) {   // prep block
        int k = threadIdx.x;
        if (k < 71) {
            float a = 0.f;
            for (int j = 0; j < 82; ++j) a += W2[k * 82 + j] * W3[j];
            w23[k] = a;
        } else if (k == 71) {
            float a = 0.f;
            for (int j = 0; j < 82; ++j) a += b2[j] * W3[j];
            w23[71] = a;
        }
        for (int i = threadIdx.x; i < 80 * WT_LD; i += 256) {
            int nn = i / WT_LD, kk = i - nn * WT_LD;
            float v = (nn < 71 && kk < 128) ? W1[kk * 71 + nn] : 0.f;
            Wt[i] = __float2half(v);
        }
        return;
    }
    __shared__ int hist[NB];
    __shared__ int gb[NB];
    __shared__ int cur[NB];
    const int BATCH = 4096;  // 16 edges / thread
    for (int base = blockIdx.x * BATCH; base < E; base += gridDim.x * BATCH) {
        for (int i = threadIdx.x; i < NB; i += blockDim.x) hist[i] = 0;
        __syncthreads();
        int s[16], d[16];
        int cnt = 0;
        if (base + BATCH <= E) {  // full batch: int4 loads
#pragma unroll
            for (int q = 0; q < 4; ++q) {
                int4 sv = ((const int4*)(src + base))[q * 256 + threadIdx.x];
                int4 dv = ((const int4*)(dst + base))[q * 256 + threadIdx.x];
                s[cnt] = sv.x; d[cnt] = dv.x; atomicAdd(&hist[dv.x >> BSHIFT], 1);
                atomicAdd(&deg_g[dv.x], 1); ++cnt;
                s[cnt] = sv.y; d[cnt] = dv.y; atomicAdd(&hist[dv.y >> BSHIFT], 1);
                atomicAdd(&deg_g[dv.y], 1); ++cnt;
                s[cnt] = sv.z; d[cnt] = dv.z; atomicAdd(&hist[dv.z >> BSHIFT], 1);
                atomicAdd(&deg_g[dv.z], 1); ++cnt;
                s[cnt] = sv.w; d[cnt] = dv.w; atomicAdd(&hist[dv.w >> BSHIFT], 1);
                atomicAdd(&deg_g[dv.w], 1); ++cnt;
            }
        } else {
#pragma unroll
            for (int k = 0; k < 16; ++k) {
                int idx = base + k * 256 + threadIdx.x;
                if (idx < E) {
                    s[cnt] = src[idx];
                    d[cnt] = dst[idx];
                    atomicAdd(&hist[d[cnt] >> BSHIFT], 1);
                    atomicAdd(&deg_g[d[cnt]], 1);
                    ++cnt;
                }
            }
        }
        __syncthreads();
        for (int i = threadIdx.x; i < NB; i += blockDim.x) {
            int c = hist[i];
            gb[i] = (c > 0) ? atomicAdd(&bcnt[i], c) : 0;
            cur[i] = 0;
        }
        __syncthreads();
        for (int k = 0; k < cnt; ++k) {
            int b = d[k] >> BSHIFT;
            int lo = gb[b] + atomicAdd(&cur[b], 1);
            if (lo < BCAP)
                bdata[(size_t)b * BCAP + lo] = ((unsigned)s[k] << BSHIFT) | ((unsigned)d[k] & BMASK);
        }
        __syncthreads();
    }
}

// ---- K3: fused binB2 (blocks 0..390) || xform (blocks 391..1953) ----
// Union LDS; binB2 computes its bucket base via wave-0 prefix over bcnt
// (kills the prep-scan dispatch); xform computes dinv on the fly from deg_g
// (kills the binB2->xform dependency).
__global__ __launch_bounds__(256) void binB2x_kernel(
        const int* __restrict__ bcnt, const unsigned* __restrict__ bdata,
        const int* __restrict__ deg_g,
        int* __restrict__ end_off, float* __restrict__ dinv,
        int* __restrict__ csr,
        const float* __restrict__ x, const __half* __restrict__ Wt,
        __half* __restrict__ msgA, __half* __restrict__ msgB, int n) {
    __shared__ __align__(16) char smem[21760];
    int tid = threadIdx.x;
    if (blockIdx.x < NB) {
        // ---- binB2 role ----
        unsigned* edata = (unsigned*)smem;           // 4864 u32 = 19456 B
        int* hist = (int*)(smem + 19456);            // 256
        int* cur  = (int*)(smem + 20480);            // 256
        int* wsum = (int*)(smem + 21504);            // 4
        int* scal = (int*)(smem + 21520);            // base, cnt
        int b = blockIdx.x;
        if (tid < 64) {   // bucket base = sum_{i<b} min(bcnt[i], BCAP)
            int s = 0;
            int lo = tid * 7, hi = min(tid * 7 + 7, b);
            for (int i = lo; i < hi; ++i) s += min(bcnt[i], BCAP);
#pragma unroll
            for (int off = 32; off; off >>= 1) s += __shfl_down(s, off);
            if (tid == 0) { scal[0] = s; scal[1] = min(bcnt[b], BCAP); }
        }
        hist[tid] = 0;
        __syncthreads();
        int cnt = scal[1];
        int base = scal[0];
        const unsigned* p = bdata + (size_t)b * BCAP;
        for (int i = tid; i < cnt; i += 256) {
            unsigned e = p[i];
            edata[i] = e;
            atomicAdd(&hist[e & BMASK], 1);
        }
        __syncthreads();
        int v = hist[tid];
        int lane = tid & 63;
        int incl = v;
#pragma unroll
        for (int off = 1; off < 64; off <<= 1) {
            int t = __shfl_up(incl, off);
            if (lane >= off) incl += t;
        }
        cur[tid] = incl;
        if (lane == 63) wsum[tid >> 6] = incl;
        __syncthreads();
        if (tid == 0) {
            int acc = 0;
#pragma unroll
            for (int w = 0; w < 4; ++w) { int t = wsum[w]; wsum[w] = acc; acc += t; }
        }
        __syncthreads();
        {
            int start = base + wsum[tid >> 6] + cur[tid] - v;  // exclusive prefix
            int node = (b << BSHIFT) + tid;
            if (node < n) {
                end_off[node] = start + v;
                dinv[node] = rsqrtf((float)v + 1.0f);
            }
            cur[tid] = start;
        }
        __syncthreads();
        for (int i = tid; i < cnt; i += 256) {
            unsigned e = edata[i];
            int pos = atomicAdd(&cur[e & BMASK], 1);
            csr[pos] = (int)(e >> BSHIFT);
        }
    } else {
        // ---- xform role: msgA/msgB = fp16( (x@W1) * rsqrt(deg+1) ) ----
        __half* Wsh = (__half*)smem;   // 80*WT_LD halves = 21760 B
        {
            const uint4* sp = (const uint4*)Wt;
            uint4* dp = (uint4*)Wsh;
            for (int i = tid; i < (80 * WT_LD * 2) / 16; i += 256) dp[i] = sp[i];
        }
        __syncthreads();
        int lane = tid & 63;
        int m = lane & 15, q = lane >> 4;
        int bx = blockIdx.x - NB;
        int gw = bx * 4 + (tid >> 6);
        int nw = NXF * 4;
        int nrt = n >> 4;  // 16-row tiles (n % 16 == 0)
        for (int rt = gw; rt < nrt; rt += nw) {
            int rb = rt << 4;
            const float* xr = x + (size_t)(rb + m) * 128 + q * 8;
            floatx4 acc[5];
#pragma unroll
            for (int t = 0; t < 5; ++t) acc[t] = (floatx4){0.f, 0.f, 0.f, 0.f};
#pragma unroll
            for (int ks = 0; ks < 4; ++ks) {
                float4 f0 = *(const float4*)(xr + ks * 32);
                float4 f1 = *(const float4*)(xr + ks * 32 + 4);
                half8 a;
                a[0] = (_Float16)f0.x; a[1] = (_Float16)f0.y;
                a[2] = (_Float16)f0.z; a[3] = (_Float16)f0.w;
                a[4] = (_Float16)f1.x; a[5] = (_Float16)f1.y;
                a[6] = (_Float16)f1.z; a[7] = (_Float16)f1.w;
#pragma unroll
                for (int t = 0; t < 5; ++t) {
                    half8 b = *(const half8*)&Wsh[(t * 16 + m) * WT_LD + ks * 32 + q * 8];
                    acc[t] = __builtin_amdgcn_mfma_f32_16x16x32_f16(a, b, acc[t], 0, 0, 0);
                }
            }
            float sc[4];
#pragma unroll
            for (int r = 0; r < 4; ++r)
                sc[r] = rsqrtf((float)deg_g[rb + q * 4 + r] + 1.0f);
#pragma unroll
            for (int t = 0; t < 5; ++t) {
                int col = t * 16 + m;
#pragma unroll
                for (int r = 0; r < 4; ++r) {
                    __half hv = __float2half(acc[t][r] * sc[r]);
                    int row = rb + q * 4 + r;
                    if (t < 4) {
                        msgA[(size_t)row * 64 + col] = hv;
                    } else if (m < 8) {
                        msgB[(size_t)row * 8 + m] = hv;   // channels 64..71 (71 = zero pad)
                    }
                }
            }
        }
    }
}

// ---- fused gather + ReLU + w23 contraction (R15 shape: best measured) ----
// 8-lane group per node, 4-slot software pipeline, NO sched_barrier (compiler
// schedules better than pinning -- R16/R17 regressions proved it).
// Self-loop = virtual edge at slot i==deg with idx=node.
__global__ __launch_bounds__(256) void gather_fused(
        const __half* __restrict__ msgA, const __half* __restrict__ msgB,
        const int* __restrict__ csr, const int* __restrict__ end_off,
        const int* __restrict__ deg, const float* __restrict__ dinv,
        const float* __restrict__ b, const float* __restrict__ w23,
        float* __restrict__ g2, int n) {
    int lane = threadIdx.x & 63;
    int li = lane & 7;                 // lane within group
    int wid = (blockIdx.x * blockDim.x + threadIdx.x) >> 6;
    int nwaves = (gridDim.x * blockDim.x) >> 6;
    float bA[8], wA[8];
#pragma unroll
    for (int j = 0; j < 8; ++j) { bA[j] = b[8 * li + j]; wA[j] = w23[8 * li + j]; }
    float bB = (li < 7) ? b[64 + li] : 0.f;
    float wB = (li < 7) ? w23[64 + li] : 0.f;      // li==7 is pad channel 71
    const char* mA = (const char*)msgA;
    const char* mB = (const char*)msgB;
    unsigned laneA   = (unsigned)(li << 4);        // byte offset in 128B A row
    unsigned laneBof = (unsigned)((li >> 1) << 2); // dword offset in 16B B row
    unsigned laneBsh = (unsigned)((li & 1) << 4);  // half-select shift
    int ntiles = n >> 3;               // n % 8 == 0 -> all nodes valid
    for (int tile = wid; tile < ntiles; tile += nwaves) {
        int node = (tile << 3) + (lane >> 3);
        int ee = end_off[node];
        int d = deg[node];
        int st = ee - d;
        float dv = dinv[node];
        int tmax = d;
        tmax = max(tmax, __shfl_xor(tmax, 8));
        tmax = max(tmax, __shfl_xor(tmax, 16));
        tmax = max(tmax, __shfl_xor(tmax, 32));
        tmax = __builtin_amdgcn_readfirstlane(tmax);
        float acc[8];
#pragma unroll
        for (int j = 0; j < 8; ++j) acc[j] = 0.f;
        float bsum = 0.f;
        // ---- prologue: csr slots 0..7, rows for slots 0..3 ----
        int c0 = csr[(0 < d) ? st + 0 : 0];
        int c1 = csr[(1 < d) ? st + 1 : 0];
        int c2 = csr[(2 < d) ? st + 2 : 0];
        int c3 = csr[(3 < d) ? st + 3 : 0];
        int c4 = csr[(4 < d) ? st + 4 : 0];
        int c5 = csr[(5 < d) ? st + 5 : 0];
        int c6 = csr[(6 < d) ? st + 6 : 0];
        int c7 = csr[(7 < d) ? st + 7 : 0];
        unsigned i0 = (unsigned)((0 < d) ? c0 : node);
        unsigned i1 = (unsigned)((1 < d) ? c1 : node);
        unsigned i2 = (unsigned)((2 < d) ? c2 : node);
        unsigned i3 = (unsigned)((3 < d) ? c3 : node);
        half8 r0 = *(const half8*)(mA + ((i0 << 7) | laneA));
        half8 r1 = *(const half8*)(mA + ((i1 << 7) | laneA));
        half8 r2 = *(const half8*)(mA + ((i2 << 7) | laneA));
        half8 r3 = *(const half8*)(mA + ((i3 << 7) | laneA));
        unsigned w0 = *(const unsigned*)(mB + ((i0 << 4) | laneBof));
        unsigned w1 = *(const unsigned*)(mB + ((i1 << 4) | laneBof));
        unsigned w2 = *(const unsigned*)(mB + ((i2 << 4) | laneBof));
        unsigned w3 = *(const unsigned*)(mB + ((i3 << 4) | laneBof));
        for (int i = 0; i <= tmax; i += 4) {
            // prefetch csr slots i+8..i+11
            int n0 = csr[(i + 8  < d) ? st + i + 8  : 0];
            int n1 = csr[(i + 9  < d) ? st + i + 9  : 0];
            int n2 = csr[(i + 10 < d) ? st + i + 10 : 0];
            int n3 = csr[(i + 11 < d) ? st + i + 11 : 0];
            // issue rows for slots i+4..i+7
            unsigned j0 = (unsigned)((i + 4 < d) ? c4 : node);
            unsigned j1 = (unsigned)((i + 5 < d) ? c5 : node);
            unsigned j2 = (unsigned)((i + 6 < d) ? c6 : node);
            unsigned j3 = (unsigned)((i + 7 < d) ? c7 : node);
            half8 s0 = *(const half8*)(mA + ((j0 << 7) | laneA));
            half8 s1 = *(const half8*)(mA + ((j1 << 7) | laneA));
            half8 s2 = *(const half8*)(mA + ((j2 << 7) | laneA));
            half8 s3 = *(const half8*)(mA + ((j3 << 7) | laneA));
            unsigned u0 = *(const unsigned*)(mB + ((j0 << 4) | laneBof));
            unsigned u1 = *(const unsigned*)(mB + ((j1 << 4) | laneBof));
            unsigned u2 = *(const unsigned*)(mB + ((j2 << 4) | laneBof));
            unsigned u3 = *(const unsigned*)(mB + ((j3 << 4) | laneBof));
            // accumulate slots i..i+3 (loaded last iteration)
            if (i <= d) {
#pragma unroll
                for (int j = 0; j < 8; ++j) acc[j] += (float)r0[j];
                unsigned short us = (unsigned short)(w0 >> laneBsh);
                _Float16 hf; __builtin_memcpy(&hf, &us, 2);
                bsum += (float)hf;
            }
            if (i + 1 <= d) {
#pragma unroll
                for (int j = 0; j < 8; ++j) acc[j] += (float)r1[j];
                unsigned short us = (unsigned short)(w1 >> laneBsh);
                _Float16 hf; __builtin_memcpy(&hf, &us, 2);
                bsum += (float)hf;
            }
            if (i + 2 <= d) {
#pragma unroll
                for (int j = 0; j < 8; ++j) acc[j] += (float)r2[j];
                unsigned short us = (unsigned short)(w2 >> laneBsh);
                _Float16 hf; __builtin_memcpy(&hf, &us, 2);
                bsum += (float)hf;
            }
            if (i + 3 <= d) {
#pragma unroll
                for (int j = 0; j < 8; ++j) acc[j] += (float)r3[j];
                unsigned short us = (unsigned short)(w3 >> laneBsh);
                _Float16 hf; __builtin_memcpy(&hf, &us, 2);
                bsum += (float)hf;
            }
            // rotate pipeline
            c4 = n0; c5 = n1; c6 = n2; c7 = n3;
            r0 = s0; r1 = s1; r2 = s2; r3 = s3;
            w0 = u0; w1 = u1; w2 = u2; w3 = u3;
        }
        float p = 0.f;
#pragma unroll
        for (int j = 0; j < 8; ++j) p += fmaxf(dv * acc[j] + bA[j], 0.f) * wA[j];
        p += fmaxf(dv * bsum + bB, 0.f) * wB;
        p += __shfl_xor(p, 1);
        p += __shfl_xor(p, 2);
        p += __shfl_xor(p, 4);
        if (li == 0) g2[node] = dv * p;
    }
}

// ---- scalar gather 1: q[i] = dinv_i * ( dinv_i*(sum g2[src] + g2[i]) + bw ) ----
__global__ void sgather_q(const float* __restrict__ g2, const int* __restrict__ csr,
                          const int* __restrict__ end_off, const int* __restrict__ deg,
                          const float* __restrict__ dinv, const float* __restrict__ w23,
                          float* __restrict__ q, int n) {
    float bw = w23[71];
    int lane = threadIdx.x & 63;
    int g = lane >> 4, k = lane & 15;
    int wid = (blockIdx.x * blockDim.x + threadIdx.x) >> 6;
    int nw = (gridDim.x * blockDim.x) >> 6;
    for (int i0 = wid * 4; i0 < n; i0 += nw * 4) {
        int i = i0 + g;
        float acc = 0.f;
        float dv = 0.f;
        if (i < n) {
            int end = end_off[i];
            int cnt = deg[i];
            int start = end - cnt;
            dv = dinv[i];
            int e = k;
            for (; e + 16 < cnt; e += 32) {
                int a0 = csr[start + e];
                int a1 = csr[start + e + 16];
                acc += g2[a0] + g2[a1];
            }
            for (; e < cnt; e += 16) acc += g2[csr[start + e]];
        }
        acc += __shfl_down(acc, 8, 16);
        acc += __shfl_down(acc, 4, 16);
        acc += __shfl_down(acc, 2, 16);
        acc += __shfl_down(acc, 1, 16);
        if (i < n && k == 0) q[i] = dv * (dv * (acc + g2[i]) + bw);
    }
}

// ---- scalar gather 2: out[i] = dinv_i*(sum q[src] + q[i]) + b3 ----
__global__ void sgather_out(const float* __restrict__ q, const int* __restrict__ csr,
                            const int* __restrict__ end_off, const int* __restrict__ deg,
                            const float* __restrict__ dinv, const float* __restrict__ b3,
                            float* __restrict__ out, int n) {
    float bv = b3[0];
    int lane = threadIdx.x & 63;
    int g = lane >> 4, k = lane & 15;
    int wid = (blockIdx.x * blockDim.x + threadIdx.x) >> 6;
    int nw = (gridDim.x * blockDim.x) >> 6;
    for (int i0 = wid * 4; i0 < n; i0 += nw * 4) {
        int i = i0 + g;
        float acc = 0.f;
        float dv = 0.f;
        if (i < n) {
            int end = end_off[i];
            int cnt = deg[i];
            int start = end - cnt;
            dv = dinv[i];
            int e = k;
            for (; e + 16 < cnt; e += 32) {
                int a0 = csr[start + e];
                int a1 = csr[start + e + 16];
                acc += q[a0] + q[a1];
            }
            for (; e < cnt; e += 16) acc += q[csr[start + e]];
        }
        acc += __shfl_down(acc, 8, 16);
        acc += __shfl_down(acc, 4, 16);
        acc += __shfl_down(acc, 2, 16);
        acc += __shfl_down(acc, 1, 16);
        if (i < n && k == 0) out[i] = dv * (acc + q[i]) + bv;
    }
}

extern "C" void kernel_launch(void* const* d_in, const int* in_sizes, int n_in,
                              void* d_out, int out_size, void* d_ws, size_t ws_size,
                              hipStream_t stream) {
    const float* x  = (const float*)d_in[0];
    const int*   ei = (const int*)d_in[1];
    const float* W1 = (const float*)d_in[2];
    const float* b1 = (const float*)d_in[3];
    const float* W2 = (const float*)d_in[4];
    const float* b2 = (const float*)d_in[5];
    const float* W3 = (const float*)d_in[6];
    const float* b3 = (const float*)d_in[7];
    float* out = (float*)d_out;

    const int n = NNODES;
    const int E = in_sizes[1] / 2;
    const int* src = ei;
    const int* dst = ei + E;

    // layout: deg_i and bcnt adjacent so one memset clears both
    int*   deg_i  = (int*)d_ws;                // n i32 (atomic counters)
    int*   bcnt   = deg_i + n;                 // 512 i32
    float* dinv   = (float*)(bcnt + 512);      // n f32
    int*   offs   = (int*)(dinv + n);          // n i32 (END offsets)
    float* w23    = (float*)(offs + n);        // 72 f32 (pad 80)
    __half* Wt    = (__half*)(w23 + 80);       // 80*WT_LD halves (pad 11008)
    float* g2     = (float*)(Wt + 11008);      // n f32
    float* q      = g2 + n;                    // n f32
    int*   csr    = (int*)(q + n);             // E i32
    __half* msgA  = (__half*)(csr + E + 16);   // +64B pad -> 128B-aligned; n*64 halves
    __half* msgB  = msgA + (size_t)n * 64;     // n*8 halves
    unsigned* bdata = (unsigned*)(msgB + (size_t)n * 8);  // NB*BCAP u32 (7.6 MB)

    // K1: zero deg counters + bucket counters (single memset)
    hipMemsetAsync(deg_i, 0, (n + 512) * sizeof(int), stream);
    // K2: bin edges + deg atomics + prep (w23, Wt) in block NB
    binAP_kernel<<<NB + 1, 256, 0, stream>>>(src, dst, bcnt, bdata, E, deg_i,
                                             W1, W2, b2, W3, w23, Wt);
    // K3: binB2 || xform fused (independent given deg_i)
    binB2x_kernel<<<NB + NXF, 256, 0, stream>>>(bcnt, bdata, deg_i, offs, dinv, csr,
                                                x, Wt, msgA, msgB, n);
    // K4: fused layer-1 gather + ReLU + (W2*W3) contraction -> scalar per node
    gather_fused<<<3125, 256, 0, stream>>>(msgA, msgB, csr, offs, deg_i, dinv, b1, w23, g2, n);
    // K5/K6: collapsed layers 2+3
    sgather_q<<<2048, 256, 0, stream>>>(g2, csr, offs, deg_i, dinv, w23, q, n);
    sgather_out<<<2048, 256, 0, stream>>>(q, csr, offs, deg_i, dinv, b3, out, n);
}

// Round 8
// 206.121 us; speedup vs baseline: 1.2303x; 1.2303x over previous
//
#include <hip/hip_runtime.h>
#include <hip/hip_fp16.h>

#define NNODES 100000
#define NB 391         // coarse buckets: node >> 8 (256 nodes each)
#define BSHIFT 8
#define BMASK 255
#define BCAP 4864      // per-bucket capacity (avg 4092, sigma ~64 -> +12 sigma)
#define WT_LD 136      // padded k-stride (halves) for transposed W1

typedef _Float16 half8 __attribute__((ext_vector_type(8)));
typedef float floatx4 __attribute__((ext_vector_type(4)));

// ---- K2: binA (1024 threads, 4 edges/thread) + prep block ----
// Blocks 0..390: coarse-bin edges. R7 evidence: 256-thread binA was latency-bound
// at 13% occupancy; 1024 threads -> 16 waves/block, scatter loop 16->4 iters.
// Block 391: w23 fold + W1 transpose/fp16 (independent of edges).
__global__ __launch_bounds__(1024) void binAP_kernel(
        const int* __restrict__ src, const int* __restrict__ dst,
        int* __restrict__ bcnt, unsigned* __restrict__ bdata, int E,
        const float* __restrict__ W1, const float* __restrict__ W2,
        const float* __restrict__ b2, const float* __restrict__ W3,
        float* __restrict__ w23, __half* __restrict__ Wt) {
    if (blockIdx.x == NB) {   // prep block
        int k = threadIdx.x;
        if (k < 71) {
            float a = 0.f;
            for (int j = 0; j < 82; ++j) a += W2[k * 82 + j] * W3[j];
            w23[k] = a;
        } else if (k == 71) {
            float a = 0.f;
            for (int j = 0; j < 82; ++j) a += b2[j] * W3[j];
            w23[71] = a;
        }
        for (int i = threadIdx.x; i < 80 * WT_LD; i += 1024) {
            int nn = i / WT_LD, kk = i - nn * WT_LD;
            float v = (nn < 71 && kk < 128) ? W1[kk * 71 + nn] : 0.f;
            Wt[i] = __float2half(v);
        }
        return;
    }
    __shared__ int hist[NB];
    __shared__ int gb[NB];
    __shared__ int cur[NB];
    const int BATCH = 4096;  // 4 edges / thread
    int tid = threadIdx.x;
    for (int base = blockIdx.x * BATCH; base < E; base += NB * BATCH) {
        for (int i = tid; i < NB; i += 1024) hist[i] = 0;
        __syncthreads();
        int s[4], d[4];
        int cnt = 0;
        if (base + BATCH <= E) {  // full batch: one int4 per thread
            int4 sv = ((const int4*)(src + base))[tid];
            int4 dv = ((const int4*)(dst + base))[tid];
            s[cnt] = sv.x; d[cnt] = dv.x; atomicAdd(&hist[dv.x >> BSHIFT], 1); ++cnt;
            s[cnt] = sv.y; d[cnt] = dv.y; atomicAdd(&hist[dv.y >> BSHIFT], 1); ++cnt;
            s[cnt] = sv.z; d[cnt] = dv.z; atomicAdd(&hist[dv.z >> BSHIFT], 1); ++cnt;
            s[cnt] = sv.w; d[cnt] = dv.w; atomicAdd(&hist[dv.w >> BSHIFT], 1); ++cnt;
        } else {
#pragma unroll
            for (int k = 0; k < 4; ++k) {
                int idx = base + k * 1024 + tid;
                if (idx < E) {
                    s[cnt] = src[idx];
                    d[cnt] = dst[idx];
                    atomicAdd(&hist[d[cnt] >> BSHIFT], 1);
                    ++cnt;
                }
            }
        }
        __syncthreads();
        for (int i = tid; i < NB; i += 1024) {
            int c = hist[i];
            gb[i] = (c > 0) ? atomicAdd(&bcnt[i], c) : 0;
            cur[i] = 0;
        }
        __syncthreads();
        for (int k = 0; k < cnt; ++k) {
            int b = d[k] >> BSHIFT;
            int lo = gb[b] + atomicAdd(&cur[b], 1);
            if (lo < BCAP)
                bdata[(size_t)b * BCAP + lo] = ((unsigned)s[k] << BSHIFT) | ((unsigned)d[k] & BMASK);
        }
        __syncthreads();
    }
}

// ---- K3: binB2 (1024 threads) with self-computed bucket base ----
// Wave 0 prefixes the 391 clamped bucket counts (R7-proven); rest is R5 shape.
__global__ __launch_bounds__(1024) void binB2_kernel(
        const int* __restrict__ bcnt, const unsigned* __restrict__ bdata,
        int* __restrict__ deg, int* __restrict__ end_off, float* __restrict__ dinv,
        int* __restrict__ csr, int n) {
    __shared__ unsigned edata[BCAP];   // 19 KB: bucket cached in LDS
    __shared__ int hist[256];
    __shared__ int cur[256];
    __shared__ int wsum[4];
    __shared__ int scal[2];
    int b = blockIdx.x;
    int tid = threadIdx.x;
    if (tid < 64) {   // bucket base = sum_{i<b} min(bcnt[i], BCAP)
        int s = 0;
        int lo = tid * 7, hi = min(tid * 7 + 7, b);
        for (int i = lo; i < hi; ++i) s += min(bcnt[i], BCAP);
#pragma unroll
        for (int off = 32; off; off >>= 1) s += __shfl_down(s, off);
        if (tid == 0) { scal[0] = s; scal[1] = min(bcnt[b], BCAP); }
    }
    if (tid < 256) hist[tid] = 0;
    __syncthreads();
    int cnt = scal[1];
    int base = scal[0];
    const unsigned* p = bdata + (size_t)b * BCAP;
    for (int i = tid; i < cnt; i += 1024) {
        unsigned e = p[i];
        edata[i] = e;
        atomicAdd(&hist[e & BMASK], 1);
    }
    __syncthreads();
    if (tid < 256) {  // 4-wave inclusive scan of hist
        int v = hist[tid];
        int lane = tid & 63;
        int incl = v;
#pragma unroll
        for (int off = 1; off < 64; off <<= 1) {
            int t = __shfl_up(incl, off);
            if (lane >= off) incl += t;
        }
        cur[tid] = incl;
        if (lane == 63) wsum[tid >> 6] = incl;
    }
    __syncthreads();
    if (tid == 0) {
        int acc = 0;
#pragma unroll
        for (int w = 0; w < 4; ++w) { int t = wsum[w]; wsum[w] = acc; acc += t; }
    }
    __syncthreads();
    if (tid < 256) {
        int v = hist[tid];
        int start = base + wsum[tid >> 6] + cur[tid] - v;  // exclusive prefix
        int node = (b << BSHIFT) + tid;
        if (node < n) {
            deg[node] = v;
            end_off[node] = start + v;
            dinv[node] = rsqrtf((float)v + 1.0f);
        }
        cur[tid] = start;
    }
    __syncthreads();
    for (int i = tid; i < cnt; i += 1024) {
        unsigned e = edata[i];
        int pos = atomicAdd(&cur[e & BMASK], 1);
        csr[pos] = (int)(e >> BSHIFT);
    }
}

// ---- K4: MFMA transform, split-channel output ----
// msgA[row][0..63] (128B rows), msgB[row][0..7] (chs 64..71, 16B rows)
__global__ __launch_bounds__(256) void xform_mfma(
        const float* __restrict__ x, const __half* __restrict__ Wt,
        const float* __restrict__ scale, __half* __restrict__ msgA,
        __half* __restrict__ msgB, int n) {
    __shared__ __half Wsh[80 * WT_LD];   // 21.25 KB
    {
        const uint4* sp = (const uint4*)Wt;
        uint4* dp = (uint4*)Wsh;
        for (int i = threadIdx.x; i < (80 * WT_LD * 2) / 16; i += blockDim.x) dp[i] = sp[i];
    }
    __syncthreads();
    int lane = threadIdx.x & 63;
    int m = lane & 15, q = lane >> 4;
    int gw = (blockIdx.x * blockDim.x + threadIdx.x) >> 6;
    int nw = (gridDim.x * blockDim.x) >> 6;
    int nrt = n >> 4;  // 16-row tiles (n % 16 == 0)
    for (int rt = gw; rt < nrt; rt += nw) {
        int rb = rt << 4;
        const float* xr = x + (size_t)(rb + m) * 128 + q * 8;
        floatx4 acc[5];
#pragma unroll
        for (int t = 0; t < 5; ++t) acc[t] = (floatx4){0.f, 0.f, 0.f, 0.f};
#pragma unroll
        for (int ks = 0; ks < 4; ++ks) {
            float4 f0 = *(const float4*)(xr + ks * 32);
            float4 f1 = *(const float4*)(xr + ks * 32 + 4);
            half8 a;
            a[0] = (_Float16)f0.x; a[1] = (_Float16)f0.y;
            a[2] = (_Float16)f0.z; a[3] = (_Float16)f0.w;
            a[4] = (_Float16)f1.x; a[5] = (_Float16)f1.y;
            a[6] = (_Float16)f1.z; a[7] = (_Float16)f1.w;
#pragma unroll
            for (int t = 0; t < 5; ++t) {
                half8 b = *(const half8*)&Wsh[(t * 16 + m) * WT_LD + ks * 32 + q * 8];
                acc[t] = __builtin_amdgcn_mfma_f32_16x16x32_f16(a, b, acc[t], 0, 0, 0);
            }
        }
        float sc[4];
#pragma unroll
        for (int r = 0; r < 4; ++r) sc[r] = scale[rb + q * 4 + r];
#pragma unroll
        for (int t = 0; t < 5; ++t) {
            int col = t * 16 + m;
#pragma unroll
            for (int r = 0; r < 4; ++r) {
                __half hv = __float2half(acc[t][r] * sc[r]);
                int row = rb + q * 4 + r;
                if (t < 4) {
                    msgA[(size_t)row * 64 + col] = hv;
                } else if (m < 8) {
                    msgB[(size_t)row * 8 + m] = hv;   // channels 64..71 (71 = zero pad)
                }
            }
        }
    }
}

// ---- K5: fused gather + ReLU + w23 contraction (R15/R4 best-measured shape) ----
// 8-lane group per node, 4-slot software pipeline, NO sched_barrier.
// Self-loop = virtual edge at slot i==deg with idx=node.
__global__ __launch_bounds__(256) void gather_fused(
        const __half* __restrict__ msgA, const __half* __restrict__ msgB,
        const int* __restrict__ csr, const int* __restrict__ end_off,
        const int* __restrict__ deg, const float* __restrict__ dinv,
        const float* __restrict__ b, const float* __restrict__ w23,
        float* __restrict__ g2, int n) {
    int lane = threadIdx.x & 63;
    int li = lane & 7;                 // lane within group
    int wid = (blockIdx.x * blockDim.x + threadIdx.x) >> 6;
    int nwaves = (gridDim.x * blockDim.x) >> 6;
    float bA[8], wA[8];
#pragma unroll
    for (int j = 0; j < 8; ++j) { bA[j] = b[8 * li + j]; wA[j] = w23[8 * li + j]; }
    float bB = (li < 7) ? b[64 + li] : 0.f;
    float wB = (li < 7) ? w23[64 + li] : 0.f;      // li==7 is pad channel 71
    const char* mA = (const char*)msgA;
    const char* mB = (const char*)msgB;
    unsigned laneA   = (unsigned)(li << 4);        // byte offset in 128B A row
    unsigned laneBof = (unsigned)((li >> 1) << 2); // dword offset in 16B B row
    unsigned laneBsh = (unsigned)((li & 1) << 4);  // half-select shift
    int ntiles = n >> 3;               // n % 8 == 0 -> all nodes valid
    for (int tile = wid; tile < ntiles; tile += nwaves) {
        int node = (tile << 3) + (lane >> 3);
        int ee = end_off[node];
        int d = deg[node];
        int st = ee - d;
        float dv = dinv[node];
        int tmax = d;
        tmax = max(tmax, __shfl_xor(tmax, 8));
        tmax = max(tmax, __shfl_xor(tmax, 16));
        tmax = max(tmax, __shfl_xor(tmax, 32));
        tmax = __builtin_amdgcn_readfirstlane(tmax);
        float acc[8];
#pragma unroll
        for (int j = 0; j < 8; ++j) acc[j] = 0.f;
        float bsum = 0.f;
        // ---- prologue: csr slots 0..7, rows for slots 0..3 ----
        int c0 = csr[(0 < d) ? st + 0 : 0];
        int c1 = csr[(1 < d) ? st + 1 : 0];
        int c2 = csr[(2 < d) ? st + 2 : 0];
        int c3 = csr[(3 < d) ? st + 3 : 0];
        int c4 = csr[(4 < d) ? st + 4 : 0];
        int c5 = csr[(5 < d) ? st + 5 : 0];
        int c6 = csr[(6 < d) ? st + 6 : 0];
        int c7 = csr[(7 < d) ? st + 7 : 0];
        unsigned i0 = (unsigned)((0 < d) ? c0 : node);
        unsigned i1 = (unsigned)((1 < d) ? c1 : node);
        unsigned i2 = (unsigned)((2 < d) ? c2 : node);
        unsigned i3 = (unsigned)((3 < d) ? c3 : node);
        half8 r0 = *(const half8*)(mA + ((i0 << 7) | laneA));
        half8 r1 = *(const half8*)(mA + ((i1 << 7) | laneA));
        half8 r2 = *(const half8*)(mA + ((i2 << 7) | laneA));
        half8 r3 = *(const half8*)(mA + ((i3 << 7) | laneA));
        unsigned w0 = *(const unsigned*)(mB + ((i0 << 4) | laneBof));
        unsigned w1 = *(const unsigned*)(mB + ((i1 << 4) | laneBof));
        unsigned w2 = *(const unsigned*)(mB + ((i2 << 4) | laneBof));
        unsigned w3 = *(const unsigned*)(mB + ((i3 << 4) | laneBof));
        for (int i = 0; i <= tmax; i += 4) {
            // prefetch csr slots i+8..i+11
            int n0 = csr[(i + 8  < d) ? st + i + 8  : 0];
            int n1 = csr[(i + 9  < d) ? st + i + 9  : 0];
            int n2 = csr[(i + 10 < d) ? st + i + 10 : 0];
            int n3 = csr[(i + 11 < d) ? st + i + 11 : 0];
            // issue rows for slots i+4..i+7
            unsigned j0 = (unsigned)((i + 4 < d) ? c4 : node);
            unsigned j1 = (unsigned)((i + 5 < d) ? c5 : node);
            unsigned j2 = (unsigned)((i + 6 < d) ? c6 : node);
            unsigned j3 = (unsigned)((i + 7 < d) ? c7 : node);
            half8 s0 = *(const half8*)(mA + ((j0 << 7) | laneA));
            half8 s1 = *(const half8*)(mA + ((j1 << 7) | laneA));
            half8 s2 = *(const half8*)(mA + ((j2 << 7) | laneA));
            half8 s3 = *(const half8*)(mA + ((j3 << 7) | laneA));
            unsigned u0 = *(const unsigned*)(mB + ((j0 << 4) | laneBof));
            unsigned u1 = *(const unsigned*)(mB + ((j1 << 4) | laneBof));
            unsigned u2 = *(const unsigned*)(mB + ((j2 << 4) | laneBof));
            unsigned u3 = *(const unsigned*)(mB + ((j3 << 4) | laneBof));
            // accumulate slots i..i+3 (loaded last iteration)
            if (i <= d) {
#pragma unroll
                for (int j = 0; j < 8; ++j) acc[j] += (float)r0[j];
                unsigned short us = (unsigned short)(w0 >> laneBsh);
                _Float16 hf; __builtin_memcpy(&hf, &us, 2);
                bsum += (float)hf;
            }
            if (i + 1 <= d) {
#pragma unroll
                for (int j = 0; j < 8; ++j) acc[j] += (float)r1[j];
                unsigned short us = (unsigned short)(w1 >> laneBsh);
                _Float16 hf; __builtin_memcpy(&hf, &us, 2);
                bsum += (float)hf;
            }
            if (i + 2 <= d) {
#pragma unroll
                for (int j = 0; j < 8; ++j) acc[j] += (float)r2[j];
                unsigned short us = (unsigned short)(w2 >> laneBsh);
                _Float16 hf; __builtin_memcpy(&hf, &us, 2);
                bsum += (float)hf;
            }
            if (i + 3 <= d) {
#pragma unroll
                for (int j = 0; j < 8; ++j) acc[j] += (float)r3[j];
                unsigned short us = (unsigned short)(w3 >> laneBsh);
                _Float16 hf; __builtin_memcpy(&hf, &us, 2);
                bsum += (float)hf;
            }
            // rotate pipeline
            c4 = n0; c5 = n1; c6 = n2; c7 = n3;
            r0 = s0; r1 = s1; r2 = s2; r3 = s3;
            w0 = u0; w1 = u1; w2 = u2; w3 = u3;
        }
        float p = 0.f;
#pragma unroll
        for (int j = 0; j < 8; ++j) p += fmaxf(dv * acc[j] + bA[j], 0.f) * wA[j];
        p += fmaxf(dv * bsum + bB, 0.f) * wB;
        p += __shfl_xor(p, 1);
        p += __shfl_xor(p, 2);
        p += __shfl_xor(p, 4);
        if (li == 0) g2[node] = dv * p;
    }
}

// ---- K6: q[i] = dinv_i * ( dinv_i*(sum g2[src] + g2[i]) + bw ) ----
__global__ void sgather_q(const float* __restrict__ g2, const int* __restrict__ csr,
                          const int* __restrict__ end_off, const int* __restrict__ deg,
                          const float* __restrict__ dinv, const float* __restrict__ w23,
                          float* __restrict__ q, int n) {
    float bw = w23[71];
    int lane = threadIdx.x & 63;
    int g = lane >> 4, k = lane & 15;
    int wid = (blockIdx.x * blockDim.x + threadIdx.x) >> 6;
    int nw = (gridDim.x * blockDim.x) >> 6;
    for (int i0 = wid * 4; i0 < n; i0 += nw * 4) {
        int i = i0 + g;
        float acc = 0.f;
        float dv = 0.f;
        if (i < n) {
            int end = end_off[i];
            int cnt = deg[i];
            int start = end - cnt;
            dv = dinv[i];
            int e = k;
            for (; e + 16 < cnt; e += 32) {
                int a0 = csr[start + e];
                int a1 = csr[start + e + 16];
                acc += g2[a0] + g2[a1];
            }
            for (; e < cnt; e += 16) acc += g2[csr[start + e]];
        }
        acc += __shfl_down(acc, 8, 16);
        acc += __shfl_down(acc, 4, 16);
        acc += __shfl_down(acc, 2, 16);
        acc += __shfl_down(acc, 1, 16);
        if (i < n && k == 0) q[i] = dv * (dv * (acc + g2[i]) + bw);
    }
}

// ---- K7: out[i] = dinv_i*(sum q[src] + q[i]) + b3 ----
__global__ void sgather_out(const float* __restrict__ q, const int* __restrict__ csr,
                            const int* __restrict__ end_off, const int* __restrict__ deg,
                            const float* __restrict__ dinv, const float* __restrict__ b3,
                            float* __restrict__ out, int n) {
    float bv = b3[0];
    int lane = threadIdx.x & 63;
    int g = lane >> 4, k = lane & 15;
    int wid = (blockIdx.x * blockDim.x + threadIdx.x) >> 6;
    int nw = (gridDim.x * blockDim.x) >> 6;
    for (int i0 = wid * 4; i0 < n; i0 += nw * 4) {
        int i = i0 + g;
        float acc = 0.f;
        float dv = 0.f;
        if (i < n) {
            int end = end_off[i];
            int cnt = deg[i];
            int start = end - cnt;
            dv = dinv[i];
            int e = k;
            for (; e + 16 < cnt; e += 32) {
                int a0 = csr[start + e];
                int a1 = csr[start + e + 16];
                acc += q[a0] + q[a1];
            }
            for (; e < cnt; e += 16) acc += q[csr[start + e]];
        }
        acc += __shfl_down(acc, 8, 16);
        acc += __shfl_down(acc, 4, 16);
        acc += __shfl_down(acc, 2, 16);
        acc += __shfl_down(acc, 1, 16);
        if (i < n && k == 0) out[i] = dv * (acc + q[i]) + bv;
    }
}

extern "C" void kernel_launch(void* const* d_in, const int* in_sizes, int n_in,
                              void* d_out, int out_size, void* d_ws, size_t ws_size,
                              hipStream_t stream) {
    const float* x  = (const float*)d_in[0];
    const int*   ei = (const int*)d_in[1];
    const float* W1 = (const float*)d_in[2];
    const float* b1 = (const float*)d_in[3];
    const float* W2 = (const float*)d_in[4];
    const float* b2 = (const float*)d_in[5];
    const float* W3 = (const float*)d_in[6];
    const float* b3 = (const float*)d_in[7];
    float* out = (float*)d_out;

    const int n = NNODES;
    const int E = in_sizes[1] / 2;
    const int* src = ei;
    const int* dst = ei + E;

    float* ws     = (float*)d_ws;
    float* dinv   = ws;                        // n f32
    int*   deg_i  = (int*)(ws + n);            // n i32
    int*   offs   = deg_i + n;                 // n i32 (END offsets)
    int*   bcnt   = offs + n;                  // 512 i32
    float* w23    = (float*)(bcnt + 512);      // 72 f32 (pad 80)
    __half* Wt    = (__half*)(w23 + 80);       // 80*WT_LD halves (pad 11008)
    float* g2     = (float*)(Wt + 11008);      // n f32
    float* q      = g2 + n;                    // n f32
    int*   csr    = (int*)(q + n);             // E i32
    __half* msgA  = (__half*)(csr + E + 16);   // +64B pad -> 128B-aligned; n*64 halves
    __half* msgB  = msgA + (size_t)n * 64;     // n*8 halves
    unsigned* bdata = (unsigned*)(msgB + (size_t)n * 8);  // NB*BCAP u32 (7.6 MB)

    // K1: zero bucket counters
    hipMemsetAsync(bcnt, 0, 512 * sizeof(int), stream);
    // K2: bin edges (1024 thr) + prep (w23, Wt) in block NB
    binAP_kernel<<<NB + 1, 1024, 0, stream>>>(src, dst, bcnt, bdata, E,
                                              W1, W2, b2, W3, w23, Wt);
    // K3: per-bucket CSR fill, self-computed bucket base
    binB2_kernel<<<NB, 1024, 0, stream>>>(bcnt, bdata, deg_i, offs, dinv, csr, n);
    // K4: msgA/msgB = fp16( (x@W1)*dinv ), split channels
    xform_mfma<<<1563, 256, 0, stream>>>(x, Wt, dinv, msgA, msgB, n);
    // K5: fused layer-1 gather + ReLU + (W2*W3) contraction -> scalar per node
    gather_fused<<<3125, 256, 0, stream>>>(msgA, msgB, csr, offs, deg_i, dinv, b1, w23, g2, n);
    // K6/K7: collapsed layers 2+3
    sgather_q<<<2048, 256, 0, stream>>>(g2, csr, offs, deg_i, dinv, w23, q, n);
    sgather_out<<<2048, 256, 0, stream>>>(q, csr, offs, deg_i, dinv, b3, out, n);
}

// Round 9
// 199.821 us; speedup vs baseline: 1.2690x; 1.0315x over previous
//
#include <hip/hip_runtime.h>
#include <hip/hip_fp16.h>

#define NNODES 100000
#define NB 391         // coarse buckets: node >> 8 (256 nodes each)
#define BSHIFT 8
#define BMASK 255
#define BCAP 4864      // per-bucket capacity (avg 4092, sigma ~64 -> +12 sigma)
#define WT_LD 136      // padded k-stride (halves) for transposed W1

typedef _Float16 half8 __attribute__((ext_vector_type(8)));
typedef float floatx4 __attribute__((ext_vector_type(4)));

// ---- K2: binA (1024 threads, 4 edges/thread, LDS-sorted coalesced flush) + prep ----
// R18: the bucket scatter is LDS-sorted per batch (rank from hist atomicAdd),
// then flushed contiguously -> ~1 line per 64B instead of 1 line RMW per 4B store.
// Block 391: w23 fold + W1 transpose/fp16 (independent of edges).
__global__ __launch_bounds__(1024) void binAP_kernel(
        const int* __restrict__ src, const int* __restrict__ dst,
        int* __restrict__ bcnt, unsigned* __restrict__ bdata, int E,
        const float* __restrict__ W1, const float* __restrict__ W2,
        const float* __restrict__ b2, const float* __restrict__ W3,
        float* __restrict__ w23, __half* __restrict__ Wt) {
    if (blockIdx.x == NB) {   // prep block
        int k = threadIdx.x;
        if (k < 71) {
            float a = 0.f;
            for (int j = 0; j < 82; ++j) a += W2[k * 82 + j] * W3[j];
            w23[k] = a;
        } else if (k == 71) {
            float a = 0.f;
            for (int j = 0; j < 82; ++j) a += b2[j] * W3[j];
            w23[71] = a;
        }
        for (int i = threadIdx.x; i < 80 * WT_LD; i += 1024) {
            int nn = i / WT_LD, kk = i - nn * WT_LD;
            float v = (nn < 71 && kk < 128) ? W1[kk * 71 + nn] : 0.f;
            Wt[i] = __float2half(v);
        }
        return;
    }
    __shared__ unsigned sorted[4096];      // 16 KB: batch sorted by bucket
    __shared__ unsigned short bkt[4096];   // 8 KB: bucket tag per sorted slot
    __shared__ int hist[NB];
    __shared__ int sbase[NB];              // batch-local exclusive bucket starts
    __shared__ int gb[NB];                 // global bucket bases for this batch
    __shared__ int wsum[8];
    int tid = threadIdx.x;
    const int BATCH = 4096;  // 4 edges / thread
    for (int base = blockIdx.x * BATCH; base < E; base += NB * BATCH) {
        int bE = min(BATCH, E - base);
        for (int i = tid; i < NB; i += 1024) hist[i] = 0;
        __syncthreads();
        int s[4], d[4], rk[4], bb[4];
        int cnt = 0;
        if (bE == BATCH) {  // full batch: one int4 per thread
            int4 sv = ((const int4*)(src + base))[tid];
            int4 dv = ((const int4*)(dst + base))[tid];
            s[0] = sv.x; d[0] = dv.x; s[1] = sv.y; d[1] = dv.y;
            s[2] = sv.z; d[2] = dv.z; s[3] = sv.w; d[3] = dv.w;
            cnt = 4;
#pragma unroll
            for (int k = 0; k < 4; ++k) {
                bb[k] = d[k] >> BSHIFT;
                rk[k] = atomicAdd(&hist[bb[k]], 1);   // rank within (batch, bucket)
            }
        } else {
#pragma unroll
            for (int k = 0; k < 4; ++k) {
                int idx = base + k * 1024 + tid;
                if (idx < E) {
                    s[cnt] = src[idx];
                    d[cnt] = dst[idx];
                    bb[cnt] = d[cnt] >> BSHIFT;
                    rk[cnt] = atomicAdd(&hist[bb[cnt]], 1);
                    ++cnt;
                }
            }
        }
        __syncthreads();
        // scan hist (391 bins, 7 waves) -> sbase; global bases via bcnt atomics
        if (tid < 448) {
            int v = (tid < NB) ? hist[tid] : 0;
            int lane = tid & 63;
            int incl = v;
#pragma unroll
            for (int off = 1; off < 64; off <<= 1) {
                int t = __shfl_up(incl, off);
                if (lane >= off) incl += t;
            }
            if (tid < NB) sbase[tid] = incl - v;
            if (lane == 63) wsum[tid >> 6] = incl;
        }
        __syncthreads();
        if (tid == 0) {
            int acc = 0;
#pragma unroll
            for (int w = 0; w < 7; ++w) { int t = wsum[w]; wsum[w] = acc; acc += t; }
        }
        __syncthreads();
        if (tid < NB) {
            sbase[tid] += wsum[tid >> 6];
            int c = hist[tid];
            gb[tid] = (c > 0) ? atomicAdd(&bcnt[tid], c) : 0;
        }
        __syncthreads();
        // scatter into LDS in bucket-sorted order
        for (int k = 0; k < cnt; ++k) {
            int pos = sbase[bb[k]] + rk[k];
            sorted[pos] = ((unsigned)s[k] << BSHIFT) | ((unsigned)d[k] & BMASK);
            bkt[pos] = (unsigned short)bb[k];
        }
        __syncthreads();
        // coalesced flush: consecutive i -> consecutive slot of same bucket chunk
        for (int i = tid; i < bE; i += 1024) {
            int bb2 = bkt[i];
            int lo = gb[bb2] + (i - sbase[bb2]);
            if (lo < BCAP)
                bdata[(size_t)bb2 * BCAP + lo] = sorted[i];
        }
        __syncthreads();
    }
}

// ---- K3: binB2 with LDS-sorted coalesced csr write ----
// R18: rank captured at hist time (regs), scan, LDS-sorted, csr flushed
// contiguously (csr[base+i] = sorted[i]) -> kills the 4B-scatter RMW traffic.
// Wave 0 computes its own bucket base (R7-proven).
__global__ __launch_bounds__(1024) void binB2_kernel(
        const int* __restrict__ bcnt, const unsigned* __restrict__ bdata,
        int* __restrict__ deg, int* __restrict__ end_off, float* __restrict__ dinv,
        int* __restrict__ csr, int n) {
    __shared__ unsigned sorted[BCAP];   // 19 KB
    __shared__ int hist[256];
    __shared__ int nstart[256];         // bucket-local exclusive node starts
    __shared__ int wsum[4];
    __shared__ int scal[2];
    int b = blockIdx.x;
    int tid = threadIdx.x;
    if (tid < 64) {   // bucket base = sum_{i<b} min(bcnt[i], BCAP)
        int s = 0;
        int lo = tid * 7, hi = min(tid * 7 + 7, b);
        for (int i = lo; i < hi; ++i) s += min(bcnt[i], BCAP);
#pragma unroll
        for (int off = 32; off; off >>= 1) s += __shfl_down(s, off);
        if (tid == 0) { scal[0] = s; scal[1] = min(bcnt[b], BCAP); }
    }
    if (tid < 256) hist[tid] = 0;
    __syncthreads();
    int cnt = scal[1];
    int base = scal[0];
    const unsigned* p = bdata + (size_t)b * BCAP;
    unsigned ev[5]; int rv[5];
    int ec = 0;
    for (int i = tid; i < cnt; i += 1024) {
        unsigned e = p[i];
        ev[ec] = e;
        rv[ec] = atomicAdd(&hist[e & BMASK], 1);   // rank within node
        ++ec;
    }
    __syncthreads();
    if (tid < 256) {  // 4-wave scan of node counts
        int v = hist[tid];
        int lane = tid & 63;
        int incl = v;
#pragma unroll
        for (int off = 1; off < 64; off <<= 1) {
            int t = __shfl_up(incl, off);
            if (lane >= off) incl += t;
        }
        nstart[tid] = incl - v;   // intra-wave exclusive (wave offset added below)
        if (lane == 63) wsum[tid >> 6] = incl;
    }
    __syncthreads();
    if (tid == 0) {
        int acc = 0;
#pragma unroll
        for (int w = 0; w < 4; ++w) { int t = wsum[w]; wsum[w] = acc; acc += t; }
    }
    __syncthreads();
    if (tid < 256) {
        int excl = nstart[tid] + wsum[tid >> 6];
        nstart[tid] = excl;
        int v = hist[tid];
        int node = (b << BSHIFT) + tid;
        if (node < n) {
            deg[node] = v;
            end_off[node] = base + excl + v;
            dinv[node] = rsqrtf((float)v + 1.0f);
        }
    }
    __syncthreads();
    for (int k = 0; k < ec; ++k) {
        unsigned e = ev[k];
        sorted[nstart[e & BMASK] + rv[k]] = e >> BSHIFT;
    }
    __syncthreads();
    for (int i = tid; i < cnt; i += 1024) csr[base + i] = (int)sorted[i];
}

// ---- K4: MFMA transform, split-channel output ----
// msgA[row][0..63] (128B rows), msgB[row][0..7] (chs 64..71, 16B rows)
__global__ __launch_bounds__(256) void xform_mfma(
        const float* __restrict__ x, const __half* __restrict__ Wt,
        const float* __restrict__ scale, __half* __restrict__ msgA,
        __half* __restrict__ msgB, int n) {
    __shared__ __half Wsh[80 * WT_LD];   // 21.25 KB
    {
        const uint4* sp = (const uint4*)Wt;
        uint4* dp = (uint4*)Wsh;
        for (int i = threadIdx.x; i < (80 * WT_LD * 2) / 16; i += blockDim.x) dp[i] = sp[i];
    }
    __syncthreads();
    int lane = threadIdx.x & 63;
    int m = lane & 15, q = lane >> 4;
    int gw = (blockIdx.x * blockDim.x + threadIdx.x) >> 6;
    int nw = (gridDim.x * blockDim.x) >> 6;
    int nrt = n >> 4;  // 16-row tiles (n % 16 == 0)
    for (int rt = gw; rt < nrt; rt += nw) {
        int rb = rt << 4;
        const float* xr = x + (size_t)(rb + m) * 128 + q * 8;
        floatx4 acc[5];
#pragma unroll
        for (int t = 0; t < 5; ++t) acc[t] = (floatx4){0.f, 0.f, 0.f, 0.f};
#pragma unroll
        for (int ks = 0; ks < 4; ++ks) {
            float4 f0 = *(const float4*)(xr + ks * 32);
            float4 f1 = *(const float4*)(xr + ks * 32 + 4);
            half8 a;
            a[0] = (_Float16)f0.x; a[1] = (_Float16)f0.y;
            a[2] = (_Float16)f0.z; a[3] = (_Float16)f0.w;
            a[4] = (_Float16)f1.x; a[5] = (_Float16)f1.y;
            a[6] = (_Float16)f1.z; a[7] = (_Float16)f1.w;
#pragma unroll
            for (int t = 0; t < 5; ++t) {
                half8 b = *(const half8*)&Wsh[(t * 16 + m) * WT_LD + ks * 32 + q * 8];
                acc[t] = __builtin_amdgcn_mfma_f32_16x16x32_f16(a, b, acc[t], 0, 0, 0);
            }
        }
        float sc[4];
#pragma unroll
        for (int r = 0; r < 4; ++r) sc[r] = scale[rb + q * 4 + r];
#pragma unroll
        for (int t = 0; t < 5; ++t) {
            int col = t * 16 + m;
#pragma unroll
            for (int r = 0; r < 4; ++r) {
                __half hv = __float2half(acc[t][r] * sc[r]);
                int row = rb + q * 4 + r;
                if (t < 4) {
                    msgA[(size_t)row * 64 + col] = hv;
                } else if (m < 8) {
                    msgB[(size_t)row * 8 + m] = hv;   // channels 64..71 (71 = zero pad)
                }
            }
        }
    }
}

// ---- K5: fused gather + ReLU + w23 contraction (R15/R4 best-measured shape) ----
// 8-lane group per node, 4-slot software pipeline, NO sched_barrier.
// Self-loop = virtual edge at slot i==deg with idx=node.
__global__ __launch_bounds__(256) void gather_fused(
        const __half* __restrict__ msgA, const __half* __restrict__ msgB,
        const int* __restrict__ csr, const int* __restrict__ end_off,
        const int* __restrict__ deg, const float* __restrict__ dinv,
        const float* __restrict__ b, const float* __restrict__ w23,
        float* __restrict__ g2, int n) {
    int lane = threadIdx.x & 63;
    int li = lane & 7;                 // lane within group
    int wid = (blockIdx.x * blockDim.x + threadIdx.x) >> 6;
    int nwaves = (gridDim.x * blockDim.x) >> 6;
    float bA[8], wA[8];
#pragma unroll
    for (int j = 0; j < 8; ++j) { bA[j] = b[8 * li + j]; wA[j] = w23[8 * li + j]; }
    float bB = (li < 7) ? b[64 + li] : 0.f;
    float wB = (li < 7) ? w23[64 + li] : 0.f;      // li==7 is pad channel 71
    const char* mA = (const char*)msgA;
    const char* mB = (const char*)msgB;
    unsigned laneA   = (unsigned)(li << 4);        // byte offset in 128B A row
    unsigned laneBof = (unsigned)((li >> 1) << 2); // dword offset in 16B B row
    unsigned laneBsh = (unsigned)((li & 1) << 4);  // half-select shift
    int ntiles = n >> 3;               // n % 8 == 0 -> all nodes valid
    for (int tile = wid; tile < ntiles; tile += nwaves) {
        int node = (tile << 3) + (lane >> 3);
        int ee = end_off[node];
        int d = deg[node];
        int st = ee - d;
        float dv = dinv[node];
        int tmax = d;
        tmax = max(tmax, __shfl_xor(tmax, 8));
        tmax = max(tmax, __shfl_xor(tmax, 16));
        tmax = max(tmax, __shfl_xor(tmax, 32));
        tmax = __builtin_amdgcn_readfirstlane(tmax);
        float acc[8];
#pragma unroll
        for (int j = 0; j < 8; ++j) acc[j] = 0.f;
        float bsum = 0.f;
        // ---- prologue: csr slots 0..7, rows for slots 0..3 ----
        int c0 = csr[(0 < d) ? st + 0 : 0];
        int c1 = csr[(1 < d) ? st + 1 : 0];
        int c2 = csr[(2 < d) ? st + 2 : 0];
        int c3 = csr[(3 < d) ? st + 3 : 0];
        int c4 = csr[(4 < d) ? st + 4 : 0];
        int c5 = csr[(5 < d) ? st + 5 : 0];
        int c6 = csr[(6 < d) ? st + 6 : 0];
        int c7 = csr[(7 < d) ? st + 7 : 0];
        unsigned i0 = (unsigned)((0 < d) ? c0 : node);
        unsigned i1 = (unsigned)((1 < d) ? c1 : node);
        unsigned i2 = (unsigned)((2 < d) ? c2 : node);
        unsigned i3 = (unsigned)((3 < d) ? c3 : node);
        half8 r0 = *(const half8*)(mA + ((i0 << 7) | laneA));
        half8 r1 = *(const half8*)(mA + ((i1 << 7) | laneA));
        half8 r2 = *(const half8*)(mA + ((i2 << 7) | laneA));
        half8 r3 = *(const half8*)(mA + ((i3 << 7) | laneA));
        unsigned w0 = *(const unsigned*)(mB + ((i0 << 4) | laneBof));
        unsigned w1 = *(const unsigned*)(mB + ((i1 << 4) | laneBof));
        unsigned w2 = *(const unsigned*)(mB + ((i2 << 4) | laneBof));
        unsigned w3 = *(const unsigned*)(mB + ((i3 << 4) | laneBof));
        for (int i = 0; i <= tmax; i += 4) {
            // prefetch csr slots i+8..i+11
            int n0 = csr[(i + 8  < d) ? st + i + 8  : 0];
            int n1 = csr[(i + 9  < d) ? st + i + 9  : 0];
            int n2 = csr[(i + 10 < d) ? st + i + 10 : 0];
            int n3 = csr[(i + 11 < d) ? st + i + 11 : 0];
            // issue rows for slots i+4..i+7
            unsigned j0 = (unsigned)((i + 4 < d) ? c4 : node);
            unsigned j1 = (unsigned)((i + 5 < d) ? c5 : node);
            unsigned j2 = (unsigned)((i + 6 < d) ? c6 : node);
            unsigned j3 = (unsigned)((i + 7 < d) ? c7 : node);
            half8 s0 = *(const half8*)(mA + ((j0 << 7) | laneA));
            half8 s1 = *(const half8*)(mA + ((j1 << 7) | laneA));
            half8 s2 = *(const half8*)(mA + ((j2 << 7) | laneA));
            half8 s3 = *(const half8*)(mA + ((j3 << 7) | laneA));
            unsigned u0 = *(const unsigned*)(mB + ((j0 << 4) | laneBof));
            unsigned u1 = *(const unsigned*)(mB + ((j1 << 4) | laneBof));
            unsigned u2 = *(const unsigned*)(mB + ((j2 << 4) | laneBof));
            unsigned u3 = *(const unsigned*)(mB + ((j3 << 4) | laneBof));
            // accumulate slots i..i+3 (loaded last iteration)
            if (i <= d) {
#pragma unroll
                for (int j = 0; j < 8; ++j) acc[j] += (float)r0[j];
                unsigned short us = (unsigned short)(w0 >> laneBsh);
                _Float16 hf; __builtin_memcpy(&hf, &us, 2);
                bsum += (float)hf;
            }
            if (i + 1 <= d) {
#pragma unroll
                for (int j = 0; j < 8; ++j) acc[j] += (float)r1[j];
                unsigned short us = (unsigned short)(w1 >> laneBsh);
                _Float16 hf; __builtin_memcpy(&hf, &us, 2);
                bsum += (float)hf;
            }
            if (i + 2 <= d) {
#pragma unroll
                for (int j = 0; j < 8; ++j) acc[j] += (float)r2[j];
                unsigned short us = (unsigned short)(w2 >> laneBsh);
                _Float16 hf; __builtin_memcpy(&hf, &us, 2);
                bsum += (float)hf;
            }
            if (i + 3 <= d) {
#pragma unroll
                for (int j = 0; j < 8; ++j) acc[j] += (float)r3[j];
                unsigned short us = (unsigned short)(w3 >> laneBsh);
                _Float16 hf; __builtin_memcpy(&hf, &us, 2);
                bsum += (float)hf;
            }
            // rotate pipeline
            c4 = n0; c5 = n1; c6 = n2; c7 = n3;
            r0 = s0; r1 = s1; r2 = s2; r3 = s3;
            w0 = u0; w1 = u1; w2 = u2; w3 = u3;
        }
        float p = 0.f;
#pragma unroll
        for (int j = 0; j < 8; ++j) p += fmaxf(dv * acc[j] + bA[j], 0.f) * wA[j];
        p += fmaxf(dv * bsum + bB, 0.f) * wB;
        p += __shfl_xor(p, 1);
        p += __shfl_xor(p, 2);
        p += __shfl_xor(p, 4);
        if (li == 0) g2[node] = dv * p;
    }
}

// ---- K6: q[i] = dinv_i * ( dinv_i*(sum g2[src] + g2[i]) + bw ) ----
__global__ void sgather_q(const float* __restrict__ g2, const int* __restrict__ csr,
                          const int* __restrict__ end_off, const int* __restrict__ deg,
                          const float* __restrict__ dinv, const float* __restrict__ w23,
                          float* __restrict__ q, int n) {
    float bw = w23[71];
    int lane = threadIdx.x & 63;
    int g = lane >> 4, k = lane & 15;
    int wid = (blockIdx.x * blockDim.x + threadIdx.x) >> 6;
    int nw = (gridDim.x * blockDim.x) >> 6;
    for (int i0 = wid * 4; i0 < n; i0 += nw * 4) {
        int i = i0 + g;
        float acc = 0.f;
        float dv = 0.f;
        if (i < n) {
            int end = end_off[i];
            int cnt = deg[i];
            int start = end - cnt;
            dv = dinv[i];
            int e = k;
            for (; e + 16 < cnt; e += 32) {
                int a0 = csr[start + e];
                int a1 = csr[start + e + 16];
                acc += g2[a0] + g2[a1];
            }
            for (; e < cnt; e += 16) acc += g2[csr[start + e]];
        }
        acc += __shfl_down(acc, 8, 16);
        acc += __shfl_down(acc, 4, 16);
        acc += __shfl_down(acc, 2, 16);
        acc += __shfl_down(acc, 1, 16);
        if (i < n && k == 0) q[i] = dv * (dv * (acc + g2[i]) + bw);
    }
}

// ---- K7: out[i] = dinv_i*(sum q[src] + q[i]) + b3 ----
__global__ void sgather_out(const float* __restrict__ q, const int* __restrict__ csr,
                            const int* __restrict__ end_off, const int* __restrict__ deg,
                            const float* __restrict__ dinv, const float* __restrict__ b3,
                            float* __restrict__ out, int n) {
    float bv = b3[0];
    int lane = threadIdx.x & 63;
    int g = lane >> 4, k = lane & 15;
    int wid = (blockIdx.x * blockDim.x + threadIdx.x) >> 6;
    int nw = (gridDim.x * blockDim.x) >> 6;
    for (int i0 = wid * 4; i0 < n; i0 += nw * 4) {
        int i = i0 + g;
        float acc = 0.f;
        float dv = 0.f;
        if (i < n) {
            int end = end_off[i];
            int cnt = deg[i];
            int start = end - cnt;
            dv = dinv[i];
            int e = k;
            for (; e + 16 < cnt; e += 32) {
                int a0 = csr[start + e];
                int a1 = csr[start + e + 16];
                acc += q[a0] + q[a1];
            }
            for (; e < cnt; e += 16) acc += q[csr[start + e]];
        }
        acc += __shfl_down(acc, 8, 16);
        acc += __shfl_down(acc, 4, 16);
        acc += __shfl_down(acc, 2, 16);
        acc += __shfl_down(acc, 1, 16);
        if (i < n && k == 0) out[i] = dv * (acc + q[i]) + bv;
    }
}

extern "C" void kernel_launch(void* const* d_in, const int* in_sizes, int n_in,
                              void* d_out, int out_size, void* d_ws, size_t ws_size,
                              hipStream_t stream) {
    const float* x  = (const float*)d_in[0];
    const int*   ei = (const int*)d_in[1];
    const float* W1 = (const float*)d_in[2];
    const float* b1 = (const float*)d_in[3];
    const float* W2 = (const float*)d_in[4];
    const float* b2 = (const float*)d_in[5];
    const float* W3 = (const float*)d_in[6];
    const float* b3 = (const float*)d_in[7];
    float* out = (float*)d_out;

    const int n = NNODES;
    const int E = in_sizes[1] / 2;
    const int* src = ei;
    const int* dst = ei + E;

    float* ws     = (float*)d_ws;
    float* dinv   = ws;                        // n f32
    int*   deg_i  = (int*)(ws + n);            // n i32
    int*   offs   = deg_i + n;                 // n i32 (END offsets)
    int*   bcnt   = offs + n;                  // 512 i32
    float* w23    = (float*)(bcnt + 512);      // 72 f32 (pad 80)
    __half* Wt    = (__half*)(w23 + 80);       // 80*WT_LD halves (pad 11008)
    float* g2     = (float*)(Wt + 11008);      // n f32
    float* q      = g2 + n;                    // n f32
    int*   csr    = (int*)(q + n);             // E i32
    __half* msgA  = (__half*)(csr + E + 16);   // +64B pad -> 128B-aligned; n*64 halves
    __half* msgB  = msgA + (size_t)n * 64;     // n*8 halves
    unsigned* bdata = (unsigned*)(msgB + (size_t)n * 8);  // NB*BCAP u32 (7.6 MB)

    // K1: zero bucket counters
    hipMemsetAsync(bcnt, 0, 512 * sizeof(int), stream);
    // K2: bin edges (1024 thr, LDS-sorted flush) + prep (w23, Wt) in block NB
    binAP_kernel<<<NB + 1, 1024, 0, stream>>>(src, dst, bcnt, bdata, E,
                                              W1, W2, b2, W3, w23, Wt);
    // K3: per-bucket CSR fill (LDS-sorted coalesced csr write)
    binB2_kernel<<<NB, 1024, 0, stream>>>(bcnt, bdata, deg_i, offs, dinv, csr, n);
    // K4: msgA/msgB = fp16( (x@W1)*dinv ), split channels
    xform_mfma<<<1563, 256, 0, stream>>>(x, Wt, dinv, msgA, msgB, n);
    // K5: fused layer-1 gather + ReLU + (W2*W3) contraction -> scalar per node
    gather_fused<<<3125, 256, 0, stream>>>(msgA, msgB, csr, offs, deg_i, dinv, b1, w23, g2, n);
    // K6/K7: collapsed layers 2+3
    sgather_q<<<2048, 256, 0, stream>>>(g2, csr, offs, deg_i, dinv, w23, q, n);
    sgather_out<<<2048, 256, 0, stream>>>(q, csr, offs, deg_i, dinv, b3, out, n);
}